// Round 9
// baseline (543.732 us; speedup 1.0000x reference)
//
#include <hip/hip_runtime.h>
#include <math.h>

typedef unsigned short u16;
typedef unsigned int u32;
typedef float f32x4 __attribute__((ext_vector_type(4)));
typedef _Float16 f16;
typedef f16 f16x8 __attribute__((ext_vector_type(8)));
typedef f16 f16x4 __attribute__((ext_vector_type(4)));
typedef u32 u32x4 __attribute__((ext_vector_type(4)));

// ---------------------------------------------------------------------------
// fp16 conv GEMM, fp32 accum, trunk fp32 (bufR) + fp16 mirror (bufT).
// R9 structure: weights global->VGPR (L2-hot frag blobs, double-buffered in
// registers, full unroll), activations staged to LDS ONCE (all 8 k-planes)
// via global_load_lds -> exactly ONE barrier per conv, zero mid-loop syncs.
// dy-row-sharing: each B-row ds_read feeds 3 dy taps x MT_W oc-frags.
// ---------------------------------------------------------------------------

__device__ u16  g_bufT[(size_t)4*128*128*64];    // trunk fp16 ch-last
__device__ float g_bufR[(size_t)4*128*128*64];   // trunk fp32 ch-last
__device__ u16  g_bufB[(size_t)4*128*128*64];    // conv1 out fp16 ch-last
__device__ u16  g_bufC[(size_t)4*4*256*256*16];  // up0 out fp16 planar16
__device__ u16  g_bufE[(size_t)4*4*512*512*16];  // up1 out fp16 planar16
__device__ float g_mod[20*4*64];
// frag blobs: [set][tap9][kf2][mt][lane64][8]
__device__ f16 g_wblk[(size_t)20*4*36864];
__device__ f16 g_wup[(size_t)2*4*36864];
__device__ f16 g_wout[9216];
__device__ u16 g_zero[8];                        // stays zero

__device__ __forceinline__ void gll16(const void* g, void* l) {
    __builtin_amdgcn_global_load_lds(
        (const __attribute__((address_space(1))) unsigned*)g,
        (__attribute__((address_space(3))) unsigned*)l, 16, 0, 0);
}

__global__ void mod_kernel(const float* __restrict__ cf,
                           const float* __restrict__ mw,
                           const float* __restrict__ mb,
                           float* __restrict__ mod) {
    int m = blockIdx.x, b = blockIdx.y, o = threadIdx.x;
    const float* wrow = mw + (m * 64 + o) * 128;
    const float* cfb  = cf + b * 128;
    float s = 0.f;
#pragma unroll 8
    for (int c = 0; c < 128; ++c) s = fmaf(cfb[c], wrow[c], s);
    mod[(m * 4 + b) * 64 + o] = s * 0.08838834764831845f + mb[m * 64 + o];
}

__global__ void prep_blk_kernel(const float* __restrict__ bw,
                                const float* __restrict__ mod,
                                f16* __restrict__ wp) {
    int c = blockIdx.x, b = blockIdx.y;
    const float s64 = 1.0f / 24.0f;
    size_t base = (size_t)(c * 4 + b) * 36864;
    for (int idx = threadIdx.x; idx < 36864; idx += 256) {
        int j = idx & 7, l = (idx >> 3) & 63;
        int frag = idx >> 9;               // [0,72)
        int mt = frag & 3, kfr = frag >> 2;
        int kf = kfr & 1, tap = kfr >> 1;
        int oc = mt * 16 + (l & 15);
        int ic = kf * 32 + (l >> 4) * 8 + j;
        float val = bw[((size_t)(c * 64 + oc) * 64 + ic) * 9 + tap] * s64 *
                    mod[(c * 4 + b) * 64 + ic];
        wp[base + idx] = (f16)val;
    }
}

__global__ void prep_up_kernel(const float* __restrict__ uw, f16* __restrict__ wp) {
    int st = blockIdx.x, ocg = blockIdx.y;
    const float s64 = 1.0f / 24.0f;
    size_t base = (size_t)(st * 4 + ocg) * 36864;
    for (int idx = threadIdx.x; idx < 36864; idx += 256) {
        int j = idx & 7, l = (idx >> 3) & 63;
        int frag = idx >> 9;
        int mt = frag & 3, kfr = frag >> 2;
        int kf = kfr & 1, tap = kfr >> 1;
        int oc = ocg * 64 + mt * 16 + (l & 15);
        int ic = kf * 32 + (l >> 4) * 8 + j;
        wp[base + idx] = (f16)(uw[((size_t)(st * 256 + oc) * 64 + ic) * 9 + tap] * s64);
    }
}

__global__ void prep_out_kernel(const float* __restrict__ ow, f16* __restrict__ wp) {
    const float s64 = 1.0f / 24.0f;
    for (int idx = threadIdx.x; idx < 9216; idx += 256) {
        int j = idx & 7, l = (idx >> 3) & 63;
        int frag = idx >> 9;               // [0,18): kf + tap*2
        int kf = frag & 1, tap = frag >> 1;
        int oc = l & 15;
        int ic = kf * 32 + (l >> 4) * 8 + j;
        float val = (oc < 3) ? ow[((size_t)(oc * 64) + ic) * 9 + tap] * s64 : 0.f;
        wp[idx] = (f16)val;
    }
}

// --- input conv (3->64, fp32 scalar), writes bufR fp32 + bufT fp16 (ch-last)
__global__ __launch_bounds__(256) void in_conv_kernel(
    const float* __restrict__ in, const float* __restrict__ wgt,
    const float* __restrict__ bias, float* __restrict__ outR,
    u16* __restrict__ outT) {
    __shared__ float slds[3][34][35];
    __shared__ float wlds[3 * 9 * 16];
    const int H = 128, W = 128;
    const int tid = threadIdx.x, x = tid & 31, yb = tid >> 5;
    const int b = blockIdx.z >> 2, ocb = (blockIdx.z & 3) * 16;
    const int tY = blockIdx.y * 32, tX = blockIdx.x * 32;
    const float s_in = 0.19245008972987526f;

    float acc[16][4];
#pragma unroll
    for (int oc = 0; oc < 16; ++oc)
#pragma unroll
        for (int k = 0; k < 4; ++k) acc[oc][k] = 0.f;

    for (int idx = tid; idx < 3 * 34 * 34; idx += 256) {
        int ic = idx / (34 * 34), p = idx % (34 * 34);
        int r = p / 34, c = p % 34;
        int gy = tY + r - 1, gx = tX + c - 1;
        float v = 0.f;
        if (gy >= 0 && gy < H && gx >= 0 && gx < W)
            v = in[((b * 3 + ic) * H + gy) * W + gx] * s_in;
        slds[ic][r][c] = v;
    }
    for (int idx = tid; idx < 3 * 9 * 16; idx += 256) {
        int oc = idx & 15, tap = (idx >> 4) % 9, ic = idx / 144;
        wlds[idx] = wgt[((ocb + oc) * 3 + ic) * 9 + tap];
    }
    __syncthreads();

#pragma unroll
    for (int ic = 0; ic < 3; ++ic)
#pragma unroll
        for (int dy = 0; dy < 3; ++dy)
#pragma unroll
            for (int dx = 0; dx < 3; ++dx) {
                float xv[4];
#pragma unroll
                for (int k = 0; k < 4; ++k)
                    xv[k] = slds[ic][yb + 8 * k + dy][x + dx];
                const float* wrow = &wlds[(ic * 9 + dy * 3 + dx) * 16];
#pragma unroll
                for (int oc = 0; oc < 16; ++oc) {
                    float wv = wrow[oc];
#pragma unroll
                    for (int k = 0; k < 4; ++k) acc[oc][k] = fmaf(wv, xv[k], acc[oc][k]);
                }
            }

#pragma unroll
    for (int oc = 0; oc < 16; ++oc) {
        int goc = ocb + oc;
        float bv = bias[goc];
#pragma unroll
        for (int k = 0; k < 4; ++k) {
            int gy = tY + yb + 8 * k, gx = tX + x;
            size_t pixG = ((size_t)b * H + gy) * W + gx;
            float v = acc[oc][k] + bv;
            outR[pixG * 64 + goc] = v;
            outT[pixG * 64 + goc] = __builtin_bit_cast(u16, (f16)v);
        }
    }
}

// --- MFMA conv, reg-A / LDS-B, single barrier.
// wave = 16 cols (cg) x ROWS rows (rg) x MT_W*16 oc (mg).
// INMODE: 1 = fp16 ch-last[64], 2 = fp16 planar16
// OUTMODE: 0 = fp16 ch-last + ReLU, 1 = fp32 trunk RMW + fp16 mirror,
//          2 = pixel-shuffle -> planar16 fp16, 3 = fp32 NCHW (oc<3)
template <int CG, int RG, int MG, int MT, int ROWS, int INMODE, int OUTMODE, int LB>
__global__ __launch_bounds__(CG* RG* MG * 64, LB) void mconv(
    const u16* __restrict__ inh, const f16* __restrict__ wp,
    const float* __restrict__ bias, float* __restrict__ rbuf,
    void* __restrict__ outv, u16* __restrict__ outT,
    int H, int W, int OCG, int wp_bstride, size_t in_pl, size_t out_pl)
{
    constexpr int TC = CG * 16, TR = RG * ROWS;
    constexpr int CST = TC + 2, RST = TR + 2;
    constexpr int PXT = RST * CST;        // granules per plane
    constexpr int MT_W = MT / MG;
    constexpr int NW = CG * RG * MG;
    constexpr int NTHR = NW * 64;
    constexpr int SB_H = 8 * PXT * 8;     // halfs: 8 planes x PXT x 16B
    constexpr int NP = 2 * TR * TC;       // out-pixel pairs (OUT2)
    constexpr int SMEM_H = (OUTMODE == 2 && 16 * NP * 2 > SB_H) ? 16 * NP * 2 : SB_H;

    __shared__ __align__(16) u16 smem[SMEM_H];

    const int tid = threadIdx.x;
    const int lane = tid & 63, wv = tid >> 6;
    const int lcol = lane & 15, lk8 = lane >> 4;
    const int cg = (CG > 1) ? (wv % CG) : 0;
    const int rg = (wv / CG) % RG;
    const int mg = wv / (CG * RG);
    const int b = blockIdx.z / OCG, ocg = blockIdx.z % OCG;
    const int y0 = blockIdx.y * TR, x0 = blockIdx.x * TC;
    const f16* wpb = wp + (size_t)b * wp_bstride + (size_t)ocg * 36864;

    auto loadA = [&](int s, f16x8(&A)[3][MT_W]) {
        int kf = s / 3, dx = s - kf * 3;
#pragma unroll
        for (int dy = 0; dy < 3; ++dy)
#pragma unroll
            for (int m = 0; m < MT_W; ++m) {
                int frag = ((dy * 3 + dx) * 2 + kf) * MT + mg * MT_W + m;
                A[dy][m] = *(const f16x8*)(wpb + (size_t)frag * 512 + (size_t)lane * 8);
            }
    };

    // A tap0 prefetch (registers), then B-stage (all 8 planes) + ONE barrier.
    f16x8 Ab[2][3][MT_W];
    loadA(0, Ab[0]);

    for (int g = tid; g < 8 * PXT; g += NTHR) {
        int pl = g / PXT, px = g - pl * PXT;
        int t = px / CST, c = px - t * CST;
        int gy = y0 + t - 1, gx = x0 + c - 1;
        const void* src = g_zero;
        if (gy >= 0 && gy < H && gx >= 0 && gx < W) {
            size_t pix = ((size_t)b * H + gy) * W + gx;
            int ic = pl * 8;
            if (INMODE == 1)
                src = inh + pix * 64 + ic;
            else
                src = inh + (size_t)(ic >> 4) * in_pl + pix * 16 + (ic & 15);
        }
        gll16(src, smem + (size_t)g * 8);
    }
    __syncthreads();

    f32x4 acc[ROWS][MT_W];
#pragma unroll
    for (int r = 0; r < ROWS; ++r)
#pragma unroll
        for (int m = 0; m < MT_W; ++m) acc[r][m] = (f32x4)0.f;

#pragma unroll
    for (int s = 0; s < 6; ++s) {
        if (s < 5) loadA(s + 1, Ab[(s + 1) & 1]);
        const int kf = s / 3, dx = s - kf * 3;
        const u16* bp = smem + (size_t)(kf * 4 + lk8) * PXT * 8;
        const int pcol = cg * 16 + dx + lcol;
#pragma unroll
        for (int iy = 0; iy < ROWS + 2; ++iy) {
            int px = (rg * ROWS + iy) * CST + pcol;
            f16x8 Bf = *(const f16x8*)(bp + (size_t)px * 8);
#pragma unroll
            for (int dy = 0; dy < 3; ++dy) {
                int r = iy - dy;
                if (r >= 0 && r < ROWS) {
#pragma unroll
                    for (int m = 0; m < MT_W; ++m)
                        acc[r][m] = __builtin_amdgcn_mfma_f32_16x16x32_f16(
                            Ab[s & 1][dy][m], Bf, acc[r][m], 0, 0, 0);
                }
            }
        }
    }

    // ---- epilogue. C/D: col(px)=lane&15, row(oc)=lk8*4+reg
    if (OUTMODE == 0 || OUTMODE == 1) {
        u16* outh = (u16*)outv;
#pragma unroll
        for (int r = 0; r < ROWS; ++r) {
            int gy = y0 + rg * ROWS + r, gx = x0 + cg * 16 + lcol;
            size_t pixG = ((size_t)b * H + gy) * W + gx;
#pragma unroll
            for (int m = 0; m < MT_W; ++m) {
                int oc0 = (mg * MT_W + m) * 16 + lk8 * 4;
                f32x4 v = acc[r][m] + *(const f32x4*)(bias + oc0);
                if (OUTMODE == 0) {
                    f16x4 o;
#pragma unroll
                    for (int j = 0; j < 4; ++j) o[j] = (f16)fmaxf(v[j], 0.f);
                    *(f16x4*)(outh + pixG * 64 + oc0) = o;
                } else {
                    float* rp = rbuf + pixG * 64 + oc0;
                    f32x4 rv = *(const f32x4*)rp;
                    v += rv;
                    *(f32x4*)rp = v;
                    f16x4 o;
#pragma unroll
                    for (int j = 0; j < 4; ++j) o[j] = (f16)v[j];
                    *(f16x4*)(outT + pixG * 64 + oc0) = o;
                }
            }
        }
    } else if (OUTMODE == 2) {
        // pixel shuffle via LDS transpose: sT[16 cc][NP pairs] u32
        __syncthreads();
        u32* sT = (u32*)smem;
#pragma unroll
        for (int r = 0; r < ROWS; ++r) {
#pragma unroll
            for (int m = 0; m < MT_W; ++m) {
                int oc0 = (mg * MT_W + m) * 16 + lk8 * 4;
                int cc = (mg * MT_W + m) * 4 + lk8;
                f32x4 v = acc[r][m] + *(const f32x4*)(bias + ocg * 64 + oc0);
                int oy = 2 * (rg * ROWS + r);
#pragma unroll
                for (int jp = 0; jp < 2; ++jp) {
                    f16 e0 = (f16)v[jp * 2], e1 = (f16)v[jp * 2 + 1];
                    u32 w = (u32)__builtin_bit_cast(u16, e0) |
                            ((u32)__builtin_bit_cast(u16, e1) << 16);
                    sT[cc * NP + (oy + jp) * TC + cg * 16 + lcol] = w;
                }
            }
        }
        __syncthreads();
        u16* outh = (u16*)outv + (size_t)ocg * out_pl;
        const int H2 = 2 * H, W2 = 2 * W;
#pragma unroll
        for (int it = 0; it < NP / NTHR; ++it) {
            int p = tid + it * NTHR;
            int oy = p / TC, xp = p - oy * TC;
            u32 tv[16];
#pragma unroll
            for (int c = 0; c < 16; ++c) tv[c] = sT[c * NP + p];
            u32 q0[8], q1[8];
#pragma unroll
            for (int c2 = 0; c2 < 8; ++c2) {
                q0[c2] = (tv[2 * c2] & 0xffffu) | (tv[2 * c2 + 1] << 16);
                q1[c2] = (tv[2 * c2] >> 16) | (tv[2 * c2 + 1] & 0xffff0000u);
            }
            int gy2 = 2 * y0 + oy, gx2 = 2 * x0 + 2 * xp;
            u16* dst = outh + (((size_t)b * H2 + gy2) * W2 + gx2) * 16;
            *(u32x4*)(dst)      = *(u32x4*)(q0);
            *(u32x4*)(dst + 8)  = *(u32x4*)(q0 + 4);
            *(u32x4*)(dst + 16) = *(u32x4*)(q1);
            *(u32x4*)(dst + 24) = *(u32x4*)(q1 + 4);
        }
    } else {
        // OUTMODE 3: fp32 NCHW, oc<3
        float* outp = (float*)outv;
        if (lk8 == 0) {
#pragma unroll
            for (int r = 0; r < ROWS; ++r) {
                int gy = y0 + rg * ROWS + r, gx = x0 + cg * 16 + lcol;
#pragma unroll
                for (int j = 0; j < 3; ++j) {
                    float v = acc[r][0][j] + bias[j];
                    outp[(((size_t)b * 3 + j) * H + gy) * W + gx] = v;
                }
            }
        }
    }
}

extern "C" void kernel_launch(void* const* d_in, const int* in_sizes, int n_in,
                              void* d_out, int out_size, void* d_ws, size_t ws_size,
                              hipStream_t stream) {
    const float* x     = (const float*)d_in[0];
    const float* cf    = (const float*)d_in[1];
    const float* in_w  = (const float*)d_in[2];
    const float* in_b  = (const float*)d_in[3];
    const float* blk_w = (const float*)d_in[4];
    const float* blk_b = (const float*)d_in[5];
    const float* mod_w = (const float*)d_in[6];
    const float* mod_b = (const float*)d_in[7];
    const float* up_w  = (const float*)d_in[8];
    const float* up_b  = (const float*)d_in[9];
    const float* out_w = (const float*)d_in[10];
    const float* out_b = (const float*)d_in[11];
    float* outp = (float*)d_out;

    u16 *bufT, *bufB, *bufC, *bufE;
    float *bufR, *modp;
    f16 *wblk, *wup, *wout;
    hipGetSymbolAddress((void**)&bufT, HIP_SYMBOL(g_bufT));
    hipGetSymbolAddress((void**)&bufR, HIP_SYMBOL(g_bufR));
    hipGetSymbolAddress((void**)&bufB, HIP_SYMBOL(g_bufB));
    hipGetSymbolAddress((void**)&bufC, HIP_SYMBOL(g_bufC));
    hipGetSymbolAddress((void**)&bufE, HIP_SYMBOL(g_bufE));
    hipGetSymbolAddress((void**)&modp, HIP_SYMBOL(g_mod));
    hipGetSymbolAddress((void**)&wblk, HIP_SYMBOL(g_wblk));
    hipGetSymbolAddress((void**)&wup,  HIP_SYMBOL(g_wup));
    hipGetSymbolAddress((void**)&wout, HIP_SYMBOL(g_wout));

    mod_kernel<<<dim3(20, 4), 64, 0, stream>>>(cf, mod_w, mod_b, modp);
    prep_blk_kernel<<<dim3(20, 4), 256, 0, stream>>>(blk_w, modp, wblk);
    prep_up_kernel<<<dim3(2, 4), 256, 0, stream>>>(up_w, wup);
    prep_out_kernel<<<1, 256, 0, stream>>>(out_w, wout);

    in_conv_kernel<<<dim3(4, 4, 16), 256, 0, stream>>>(x, in_w, in_b, bufR, bufT);

    const size_t PLC = (size_t)4 * 256 * 256 * 16;
    const size_t PLE = (size_t)4 * 512 * 512 * 16;

    for (int i = 0; i < 10; ++i) {
        // conv1: bufT -> bufB (fp16, ReLU). tile 16x8, 512 blocks.
        mconv<1, 2, 2, 4, 4, 1, 0, 3><<<dim3(8, 16, 4), 256, 0, stream>>>(
            bufT, wblk + (size_t)(2 * i) * 4 * 36864, blk_b + (2 * i) * 64,
            nullptr, bufB, nullptr, 128, 128, 1, 36864, 0, 0);
        // conv2: bufB -> trunk RMW (bufR fp32) + bufT mirror
        mconv<1, 2, 2, 4, 4, 1, 1, 3><<<dim3(8, 16, 4), 256, 0, stream>>>(
            bufB, wblk + (size_t)(2 * i + 1) * 4 * 36864, blk_b + (2 * i + 1) * 64,
            bufR, nullptr, bufT, 128, 128, 1, 36864, 0, 0);
    }

    // up0: bufT @128^2 -> shuffle -> bufC (planar16, 256^2). tile 32x8.
    mconv<2, 1, 2, 4, 8, 1, 2, 3><<<dim3(4, 16, 16), 256, 0, stream>>>(
        bufT, wup, up_b, nullptr, bufC, nullptr, 128, 128, 4, 0, 0, PLC);
    // up1: bufC @256^2 -> shuffle -> bufE (planar16, 512^2). tile 32x8.
    mconv<2, 1, 2, 4, 8, 2, 2, 3><<<dim3(8, 32, 16), 256, 0, stream>>>(
        bufC, wup + (size_t)4 * 36864, up_b + 256, nullptr, bufE, nullptr,
        256, 256, 4, 0, PLC, PLE);
    // out: bufE @512^2 -> fp32 NCHW (3 ch). tile 32x8.
    mconv<2, 2, 1, 1, 4, 2, 3, 4><<<dim3(16, 64, 4), 256, 0, stream>>>(
        bufE, wout, out_b, nullptr, outp, nullptr, 512, 512, 1, 0, PLE, 0);
}

// Round 11
// 486.764 us; speedup vs baseline: 1.1170x; 1.1170x over previous
//
#include <hip/hip_runtime.h>
#include <math.h>

typedef unsigned short u16;
typedef unsigned int u32;
typedef float f32x4 __attribute__((ext_vector_type(4)));
typedef _Float16 f16;
typedef f16 f16x8 __attribute__((ext_vector_type(8)));
typedef f16 f16x4 __attribute__((ext_vector_type(4)));
typedef u32 u32x4 __attribute__((ext_vector_type(4)));

// ---------------------------------------------------------------------------
// fp16 conv GEMM, fp32 accum, trunk fp32 (bufR) + fp16 planar16 mirror (bufT).
// R11 = R10 structure with the gll16-divergence bug fixed: the staging loop
// NEVER skips a gll16 (pad slots read g_zero) so the wave's LDS writes stay
// lane-linear (global_load_lds base comes from the first ACTIVE lane; masking
// leading lanes shifts the whole wave's writes — the R10 corruption).
// (1) ocg-loop: up-convs stage B once, compute 4 oc-groups; (2) planar16
// activations -> line-contiguous staging; (3) padded B plane stride and sT
// rows to break bank-group alignment. Weights global->VGPR double-buffered.
// ---------------------------------------------------------------------------

__device__ u16  g_bufT[(size_t)4*128*128*64];    // trunk fp16 planar16
__device__ float g_bufR[(size_t)4*128*128*64];   // trunk fp32 ch-last
__device__ u16  g_bufB[(size_t)4*128*128*64];    // conv1 out fp16 planar16
__device__ u16  g_bufC[(size_t)4*4*256*256*16];  // up0 out fp16 planar16
__device__ u16  g_bufE[(size_t)4*4*512*512*16];  // up1 out fp16 planar16
__device__ float g_mod[20*4*64];
// frag blobs: [set][tap9][kf2][mt][lane64][8]
__device__ f16 g_wblk[(size_t)20*4*36864];
__device__ f16 g_wup[(size_t)2*4*36864];
__device__ f16 g_wout[9216];
__device__ u16 g_zero[8];                        // stays zero

__device__ __forceinline__ void gll16(const void* g, void* l) {
    __builtin_amdgcn_global_load_lds(
        (const __attribute__((address_space(1))) unsigned*)g,
        (__attribute__((address_space(3))) unsigned*)l, 16, 0, 0);
}

__global__ void mod_kernel(const float* __restrict__ cf,
                           const float* __restrict__ mw,
                           const float* __restrict__ mb,
                           float* __restrict__ mod) {
    int m = blockIdx.x, b = blockIdx.y, o = threadIdx.x;
    const float* wrow = mw + (m * 64 + o) * 128;
    const float* cfb  = cf + b * 128;
    float s = 0.f;
#pragma unroll 8
    for (int c = 0; c < 128; ++c) s = fmaf(cfb[c], wrow[c], s);
    mod[(m * 4 + b) * 64 + o] = s * 0.08838834764831845f + mb[m * 64 + o];
}

__global__ void prep_blk_kernel(const float* __restrict__ bw,
                                const float* __restrict__ mod,
                                f16* __restrict__ wp) {
    int c = blockIdx.x, b = blockIdx.y;
    const float s64 = 1.0f / 24.0f;
    size_t base = (size_t)(c * 4 + b) * 36864;
    for (int idx = threadIdx.x; idx < 36864; idx += 256) {
        int j = idx & 7, l = (idx >> 3) & 63;
        int frag = idx >> 9;               // [0,72)
        int mt = frag & 3, kfr = frag >> 2;
        int kf = kfr & 1, tap = kfr >> 1;
        int oc = mt * 16 + (l & 15);
        int ic = kf * 32 + (l >> 4) * 8 + j;
        float val = bw[((size_t)(c * 64 + oc) * 64 + ic) * 9 + tap] * s64 *
                    mod[(c * 4 + b) * 64 + ic];
        wp[base + idx] = (f16)val;
    }
}

__global__ void prep_up_kernel(const float* __restrict__ uw, f16* __restrict__ wp) {
    int st = blockIdx.x, ocg = blockIdx.y;
    const float s64 = 1.0f / 24.0f;
    size_t base = (size_t)(st * 4 + ocg) * 36864;
    for (int idx = threadIdx.x; idx < 36864; idx += 256) {
        int j = idx & 7, l = (idx >> 3) & 63;
        int frag = idx >> 9;
        int mt = frag & 3, kfr = frag >> 2;
        int kf = kfr & 1, tap = kfr >> 1;
        int oc = ocg * 64 + mt * 16 + (l & 15);
        int ic = kf * 32 + (l >> 4) * 8 + j;
        wp[base + idx] = (f16)(uw[((size_t)(st * 256 + oc) * 64 + ic) * 9 + tap] * s64);
    }
}

__global__ void prep_out_kernel(const float* __restrict__ ow, f16* __restrict__ wp) {
    const float s64 = 1.0f / 24.0f;
    for (int idx = threadIdx.x; idx < 9216; idx += 256) {
        int j = idx & 7, l = (idx >> 3) & 63;
        int frag = idx >> 9;               // [0,18): kf + tap*2
        int kf = frag & 1, tap = frag >> 1;
        int oc = l & 15;
        int ic = kf * 32 + (l >> 4) * 8 + j;
        float val = (oc < 3) ? ow[((size_t)(oc * 64) + ic) * 9 + tap] * s64 : 0.f;
        wp[idx] = (f16)val;
    }
}

// --- input conv (3->64, fp32 scalar), writes bufR fp32 ch-last + bufT planar16
__global__ __launch_bounds__(256) void in_conv_kernel(
    const float* __restrict__ in, const float* __restrict__ wgt,
    const float* __restrict__ bias, float* __restrict__ outR,
    u16* __restrict__ outT) {
    __shared__ float slds[3][34][35];
    __shared__ float wlds[3 * 9 * 16];
    const int H = 128, W = 128;
    const size_t PLT = (size_t)4 * 128 * 128 * 16;
    const int tid = threadIdx.x, x = tid & 31, yb = tid >> 5;
    const int b = blockIdx.z >> 2, ocb = (blockIdx.z & 3) * 16;
    const int tY = blockIdx.y * 32, tX = blockIdx.x * 32;
    const float s_in = 0.19245008972987526f;

    float acc[16][4];
#pragma unroll
    for (int oc = 0; oc < 16; ++oc)
#pragma unroll
        for (int k = 0; k < 4; ++k) acc[oc][k] = 0.f;

    for (int idx = tid; idx < 3 * 34 * 34; idx += 256) {
        int ic = idx / (34 * 34), p = idx % (34 * 34);
        int r = p / 34, c = p % 34;
        int gy = tY + r - 1, gx = tX + c - 1;
        float v = 0.f;
        if (gy >= 0 && gy < H && gx >= 0 && gx < W)
            v = in[((b * 3 + ic) * H + gy) * W + gx] * s_in;
        slds[ic][r][c] = v;
    }
    for (int idx = tid; idx < 3 * 9 * 16; idx += 256) {
        int oc = idx & 15, tap = (idx >> 4) % 9, ic = idx / 144;
        wlds[idx] = wgt[((ocb + oc) * 3 + ic) * 9 + tap];
    }
    __syncthreads();

#pragma unroll
    for (int ic = 0; ic < 3; ++ic)
#pragma unroll
        for (int dy = 0; dy < 3; ++dy)
#pragma unroll
            for (int dx = 0; dx < 3; ++dx) {
                float xv[4];
#pragma unroll
                for (int k = 0; k < 4; ++k)
                    xv[k] = slds[ic][yb + 8 * k + dy][x + dx];
                const float* wrow = &wlds[(ic * 9 + dy * 3 + dx) * 16];
#pragma unroll
                for (int oc = 0; oc < 16; ++oc) {
                    float wv = wrow[oc];
#pragma unroll
                    for (int k = 0; k < 4; ++k) acc[oc][k] = fmaf(wv, xv[k], acc[oc][k]);
                }
            }

#pragma unroll
    for (int oc = 0; oc < 16; ++oc) {
        int goc = ocb + oc;
        float bv = bias[goc];
#pragma unroll
        for (int k = 0; k < 4; ++k) {
            int gy = tY + yb + 8 * k, gx = tX + x;
            size_t pixG = ((size_t)b * H + gy) * W + gx;
            float v = acc[oc][k] + bv;
            outR[pixG * 64 + goc] = v;
            outT[(size_t)(goc >> 4) * PLT + pixG * 16 + (goc & 15)] =
                __builtin_bit_cast(u16, (f16)v);
        }
    }
}

// --- MFMA conv, reg-A / LDS-B, one stage barrier, ocg-loop.
// wave = 16 cols (cg) x ROWS rows (rg) x MT_W*16 oc (mg).
// Input: always fp16 planar16 (in_pl = plane stride in halfs).
// OUTMODE: 0 = fp16 planar16 + ReLU, 1 = fp32 trunk RMW + planar16 mirror,
//          2 = pixel-shuffle -> planar16 fp16, 3 = fp32 NCHW (oc<3)
template <int CG, int RG, int MG, int MT, int ROWS, int NOCG, int OUTMODE, int LB>
__global__ __launch_bounds__(CG* RG* MG * 64, LB) void mconv(
    const u16* __restrict__ inh, const f16* __restrict__ wp,
    const float* __restrict__ bias, float* __restrict__ rbuf,
    void* __restrict__ outv, u16* __restrict__ outT,
    int H, int W, int wp_bstride, size_t in_pl, size_t out_pl)
{
    constexpr int TC = CG * 16, TR = RG * ROWS;
    constexpr int CST = TC + 2, RST = TR + 2;
    constexpr int PXT = RST * CST;                       // granules per plane
    constexpr int PXS = PXT + ((2 - (PXT & 7) + 8) & 7); // ≡2 mod 8 -> 32B offset
    constexpr int MT_W = MT / MG;
    constexpr int NW = CG * RG * MG;
    constexpr int NTHR = NW * 64;
    constexpr int SB_H = 8 * PXS * 8;                    // halfs
    constexpr int NPP = 8 * TC + 8;                      // sT padded row stride
    constexpr int ST_H = (OUTMODE == 2) ? 16 * NPP * 2 : 0;

    __shared__ __align__(16) u16 smem[SB_H + ST_H];
    u32* sT = (u32*)(smem + SB_H);

    const int tid = threadIdx.x;
    const int lane = tid & 63, wv = tid >> 6;
    const int lcol = lane & 15, lk8 = lane >> 4;
    const int cg = (CG > 1) ? (wv % CG) : 0;
    const int rg = (wv / CG) % RG;
    const int mg = wv / (CG * RG);
    const int b = blockIdx.z;
    const int y0 = blockIdx.y * TR, x0 = blockIdx.x * TC;

    auto loadA = [&](int ocg, int s, f16x8(&A)[3][MT_W]) {
        int kf = s / 3, dx = s - kf * 3;
        const f16* base = wp + (size_t)b * wp_bstride + (size_t)ocg * 36864;
#pragma unroll
        for (int dy = 0; dy < 3; ++dy)
#pragma unroll
            for (int m = 0; m < MT_W; ++m) {
                int frag = ((dy * 3 + dx) * 2 + kf) * MT + mg * MT_W + m;
                A[dy][m] = *(const f16x8*)(base + (size_t)frag * 512 + (size_t)lane * 8);
            }
    };

    f16x8 Ab[2][3][MT_W];
    loadA(0, 0, Ab[0]);

    // stage B: 8 planes (padded stride), planar16 source (line-contiguous).
    // CRITICAL: every lane in range issues gll16 (pad slots -> g_zero) so the
    // wave's LDS writes stay lane-linear (no leading-lane masking).
    for (int g = tid; g < 8 * PXS; g += NTHR) {
        int pl = g / PXS, px = g - pl * PXS;
        int t = px / CST, c = px - t * CST;
        int gy = y0 + t - 1, gx = x0 + c - 1;
        const void* src = g_zero;
        if (px < PXT && gy >= 0 && gy < H && gx >= 0 && gx < W) {
            size_t pix = ((size_t)b * H + gy) * W + gx;
            src = inh + (size_t)(pl >> 1) * in_pl + pix * 16 + (pl & 1) * 8;
        }
        gll16(src, smem + (size_t)g * 8);
    }
    __syncthreads();

#pragma unroll 1
    for (int o = 0; o < NOCG; ++o) {
        f32x4 acc[ROWS][MT_W];
#pragma unroll
        for (int r = 0; r < ROWS; ++r)
#pragma unroll
            for (int m = 0; m < MT_W; ++m) acc[r][m] = (f32x4)0.f;

#pragma unroll
        for (int s = 0; s < 6; ++s) {
            if (s < 5) loadA(o, s + 1, Ab[(s + 1) & 1]);
            else if (o + 1 < NOCG) loadA(o + 1, 0, Ab[0]);
            const int kf = s / 3, dx = s - kf * 3;
            const u16* bp = smem + (size_t)(kf * 4 + lk8) * PXS * 8;
            const int pcol = cg * 16 + dx + lcol;
#pragma unroll
            for (int iy = 0; iy < ROWS + 2; ++iy) {
                int px = (rg * ROWS + iy) * CST + pcol;
                f16x8 Bf = *(const f16x8*)(bp + (size_t)px * 8);
#pragma unroll
                for (int dy = 0; dy < 3; ++dy) {
                    int r = iy - dy;
                    if (r >= 0 && r < ROWS) {
#pragma unroll
                        for (int m = 0; m < MT_W; ++m)
                            acc[r][m] = __builtin_amdgcn_mfma_f32_16x16x32_f16(
                                Ab[s & 1][dy][m], Bf, acc[r][m], 0, 0, 0);
                    }
                }
            }
        }

        // ---- epilogue. C/D: col(px)=lane&15, row(oc)=lk8*4+reg
        if (OUTMODE == 0 || OUTMODE == 1) {
            u16* outh = (u16*)outv;
#pragma unroll
            for (int r = 0; r < ROWS; ++r) {
                int gy = y0 + rg * ROWS + r, gx = x0 + cg * 16 + lcol;
                size_t pixG = ((size_t)b * H + gy) * W + gx;
#pragma unroll
                for (int m = 0; m < MT_W; ++m) {
                    int oc0 = (mg * MT_W + m) * 16 + lk8 * 4;
                    f32x4 v = acc[r][m] + *(const f32x4*)(bias + oc0);
                    if (OUTMODE == 0) {
                        f16x4 ov;
#pragma unroll
                        for (int j = 0; j < 4; ++j) ov[j] = (f16)fmaxf(v[j], 0.f);
                        *(f16x4*)(outh + (size_t)(oc0 >> 4) * out_pl + pixG * 16 + (oc0 & 15)) = ov;
                    } else {
                        float* rp = rbuf + pixG * 64 + oc0;
                        f32x4 rv = *(const f32x4*)rp;
                        v += rv;
                        *(f32x4*)rp = v;
                        f16x4 ov;
#pragma unroll
                        for (int j = 0; j < 4; ++j) ov[j] = (f16)v[j];
                        *(f16x4*)(outT + (size_t)(oc0 >> 4) * out_pl + pixG * 16 + (oc0 & 15)) = ov;
                    }
                }
            }
        } else if (OUTMODE == 2) {
            // pixel shuffle: TR/4 passes of 4 in-rows (8 out-rows) via sT
            u16* outh = (u16*)outv + (size_t)o * out_pl;
            const int H2 = 2 * H, W2 = 2 * W;
#pragma unroll
            for (int p = 0; p < TR / 4; ++p) {
#pragma unroll
                for (int r = 0; r < ROWS; ++r) {
                    int ri = rg * ROWS + r;
                    if (ri >= p * 4 && ri < p * 4 + 4) {
#pragma unroll
                        for (int m = 0; m < MT_W; ++m) {
                            int oc0 = (mg * MT_W + m) * 16 + lk8 * 4;
                            int cc = (mg * MT_W + m) * 4 + lk8;
                            f32x4 v = acc[r][m] + *(const f32x4*)(bias + o * 64 + oc0);
                            int oyl = 2 * (ri - p * 4);
#pragma unroll
                            for (int jp = 0; jp < 2; ++jp) {
                                f16 e0 = (f16)v[jp * 2], e1 = (f16)v[jp * 2 + 1];
                                u32 w = (u32)__builtin_bit_cast(u16, e0) |
                                        ((u32)__builtin_bit_cast(u16, e1) << 16);
                                sT[cc * NPP + (oyl + jp) * TC + cg * 16 + lcol] = w;
                            }
                        }
                    }
                }
                __syncthreads();
                if (tid < 8 * TC) {
                    int oyl = tid / TC, xp = tid - oyl * TC;
                    u32 tv[16];
#pragma unroll
                    for (int c = 0; c < 16; ++c) tv[c] = sT[c * NPP + oyl * TC + xp];
                    u32 q0[8], q1[8];
#pragma unroll
                    for (int c2 = 0; c2 < 8; ++c2) {
                        q0[c2] = (tv[2 * c2] & 0xffffu) | (tv[2 * c2 + 1] << 16);
                        q1[c2] = (tv[2 * c2] >> 16) | (tv[2 * c2 + 1] & 0xffff0000u);
                    }
                    int gy2 = 2 * y0 + p * 8 + oyl, gx2 = 2 * x0 + 2 * xp;
                    u16* dst = outh + (((size_t)b * H2 + gy2) * W2 + gx2) * 16;
                    *(u32x4*)(dst)      = *(u32x4*)(q0);
                    *(u32x4*)(dst + 8)  = *(u32x4*)(q0 + 4);
                    *(u32x4*)(dst + 16) = *(u32x4*)(q1);
                    *(u32x4*)(dst + 24) = *(u32x4*)(q1 + 4);
                }
                __syncthreads();
            }
        } else {
            // OUTMODE 3: fp32 NCHW, oc<3
            float* outp = (float*)outv;
            if (lk8 == 0) {
#pragma unroll
                for (int r = 0; r < ROWS; ++r) {
                    int gy = y0 + rg * ROWS + r, gx = x0 + cg * 16 + lcol;
#pragma unroll
                    for (int j = 0; j < 3; ++j) {
                        float v = acc[r][0][j] + bias[j];
                        outp[(((size_t)b * 3 + j) * H + gy) * W + gx] = v;
                    }
                }
            }
        }
    }
}

extern "C" void kernel_launch(void* const* d_in, const int* in_sizes, int n_in,
                              void* d_out, int out_size, void* d_ws, size_t ws_size,
                              hipStream_t stream) {
    const float* x     = (const float*)d_in[0];
    const float* cf    = (const float*)d_in[1];
    const float* in_w  = (const float*)d_in[2];
    const float* in_b  = (const float*)d_in[3];
    const float* blk_w = (const float*)d_in[4];
    const float* blk_b = (const float*)d_in[5];
    const float* mod_w = (const float*)d_in[6];
    const float* mod_b = (const float*)d_in[7];
    const float* up_w  = (const float*)d_in[8];
    const float* up_b  = (const float*)d_in[9];
    const float* out_w = (const float*)d_in[10];
    const float* out_b = (const float*)d_in[11];
    float* outp = (float*)d_out;

    u16 *bufT, *bufB, *bufC, *bufE;
    float *bufR, *modp;
    f16 *wblk, *wup, *wout;
    hipGetSymbolAddress((void**)&bufT, HIP_SYMBOL(g_bufT));
    hipGetSymbolAddress((void**)&bufR, HIP_SYMBOL(g_bufR));
    hipGetSymbolAddress((void**)&bufB, HIP_SYMBOL(g_bufB));
    hipGetSymbolAddress((void**)&bufC, HIP_SYMBOL(g_bufC));
    hipGetSymbolAddress((void**)&bufE, HIP_SYMBOL(g_bufE));
    hipGetSymbolAddress((void**)&modp, HIP_SYMBOL(g_mod));
    hipGetSymbolAddress((void**)&wblk, HIP_SYMBOL(g_wblk));
    hipGetSymbolAddress((void**)&wup,  HIP_SYMBOL(g_wup));
    hipGetSymbolAddress((void**)&wout, HIP_SYMBOL(g_wout));

    mod_kernel<<<dim3(20, 4), 64, 0, stream>>>(cf, mod_w, mod_b, modp);
    prep_blk_kernel<<<dim3(20, 4), 256, 0, stream>>>(blk_w, modp, wblk);
    prep_up_kernel<<<dim3(2, 4), 256, 0, stream>>>(up_w, wup);
    prep_out_kernel<<<1, 256, 0, stream>>>(out_w, wout);

    in_conv_kernel<<<dim3(4, 4, 16), 256, 0, stream>>>(x, in_w, in_b, bufR, bufT);

    const size_t PLT = (size_t)4 * 128 * 128 * 16;
    const size_t PLC = (size_t)4 * 256 * 256 * 16;
    const size_t PLE = (size_t)4 * 512 * 512 * 16;

    for (int i = 0; i < 10; ++i) {
        // conv1: bufT -> bufB (planar16, ReLU). tile 16x8, 512 blocks.
        mconv<1, 2, 2, 4, 4, 1, 0, 3><<<dim3(8, 16, 4), 256, 0, stream>>>(
            bufT, wblk + (size_t)(2 * i) * 4 * 36864, blk_b + (2 * i) * 64,
            nullptr, bufB, nullptr, 128, 128, 36864, PLT, PLT);
        // conv2: bufB -> trunk RMW (bufR fp32) + bufT planar16 mirror
        mconv<1, 2, 2, 4, 4, 1, 1, 3><<<dim3(8, 16, 4), 256, 0, stream>>>(
            bufB, wblk + (size_t)(2 * i + 1) * 4 * 36864, blk_b + (2 * i + 1) * 64,
            bufR, nullptr, bufT, 128, 128, 36864, PLT, PLT);
    }

    // up0: bufT @128^2, ocg-loop x4 -> shuffle -> bufC. tile 16x8, 512 blocks.
    mconv<1, 2, 2, 4, 4, 4, 2, 3><<<dim3(8, 16, 4), 256, 0, stream>>>(
        bufT, wup, up_b, nullptr, bufC, nullptr, 128, 128, 0, PLT, PLC);
    // up1: bufC @256^2, ocg-loop x4 -> shuffle -> bufE. tile 32x8, 1024 blocks.
    mconv<2, 1, 2, 4, 8, 4, 2, 2><<<dim3(8, 32, 4), 256, 0, stream>>>(
        bufC, wup + (size_t)4 * 36864, up_b + 256, nullptr, bufE, nullptr,
        256, 256, 0, PLC, PLE);
    // out: bufE @512^2 -> fp32 NCHW (3 ch). tile 32x16, 4096 blocks.
    mconv<2, 2, 1, 1, 4, 1, 3, 3><<<dim3(16, 64, 4), 256, 0, stream>>>(
        bufE, wout, out_b, nullptr, outp, nullptr, 512, 512, 0, PLE, 0);
}